// Round 4
// baseline (304.474 us; speedup 1.0000x reference)
//
#include <hip/hip_runtime.h>
#include <stdint.h>

typedef unsigned short u16;
typedef float f32x4 __attribute__((ext_vector_type(4)));
typedef _Float16 half8 __attribute__((ext_vector_type(8)));
typedef __fp16 fp16x2 __attribute__((ext_vector_type(2)));

#define B_  8
#define M_  2
#define DK_ 512
#define D_  256
#define N_  2048
#define DV_ 512

#define OUT_FLOATS (B_*N_*DV_)     /* 8388608 */
#define QB_U16     (B_*M_*N_*D_)   /* 8388608 u16 elements = 16 MiB */

// ---- fp16 pack/unpack helpers -------------------------------------------
__device__ __forceinline__ uint32_t pk16(float a, float b){
    fp16x2 h = __builtin_amdgcn_cvt_pkrtz(a, b);      // v_cvt_pkrtz_f16_f32
    return __builtin_bit_cast(uint32_t, h);
}
__device__ __forceinline__ float h2f_lo(uint32_t u){
    return (float)__builtin_bit_cast(_Float16, (unsigned short)(u & 0xffffu));
}
__device__ __forceinline__ float h2f_hi(uint32_t u){
    return (float)__builtin_bit_cast(_Float16, (unsigned short)(u >> 16));
}

// ============================================================
// K0: transpose-convert qt,kt (fp32 [b, m*256+c, i]) -> f16 [ (b*2+m), row, c ]
// staged into the d_out "output" region. Also folds bar-sum (k1):
// atomicAdd per-c partial sums of qt into wsBar.
// ============================================================
__global__ __launch_bounds__(256) void k0_transpose(const float* __restrict__ qt,
                                                    const float* __restrict__ kt,
                                                    u16* __restrict__ dstBase,
                                                    float* __restrict__ wsBar){
    const int it = blockIdx.x, yc = blockIdx.y, z = blockIdx.z;
    const int b = z & 7, src = z >> 3;
    const float* sp = src ? kt : qt;
    u16* dp = dstBase + (size_t)src * QB_U16;
    const int m = yc >> 2;
    const int cbase = (yc & 3) * 64;
    const int i0 = it * 64;
    __shared__ u16 lds[64 * 72];   // [i][c], pad 72 keeps 16B alignment
    const int t = threadIdx.x;
    {
        const int c_loc = t >> 2;
        const int iq = (t & 3) * 16;
        const float* g = sp + (size_t)(b*DK_ + m*D_ + cbase + c_loc) * N_ + i0 + iq;
        float vv[16];
        *(float4*)&vv[0]  = *(const float4*)(g + 0);
        *(float4*)&vv[4]  = *(const float4*)(g + 4);
        *(float4*)&vv[8]  = *(const float4*)(g + 8);
        *(float4*)&vv[12] = *(const float4*)(g + 12);
        #pragma unroll
        for (int e = 0; e < 16; ++e){
            _Float16 hf = (_Float16)vv[e];
            lds[(iq + e)*72 + c_loc] = __builtin_bit_cast(unsigned short, hf);
        }
        if (src == 0){   // folded k1: partial sum over this thread's 16 i
            float s = 0.f;
            #pragma unroll
            for (int e = 0; e < 16; ++e) s += vv[e];
            s += __shfl_xor(s, 1);
            s += __shfl_xor(s, 2);
            if ((t & 3) == 0)
                atomicAdd(&wsBar[b*DK_ + m*D_ + cbase + c_loc], s);
        }
    }
    __syncthreads();
    {
        const int i_loc = t >> 2;
        const int cq = (t & 3) * 16;
        uint4 a  = *(const uint4*)&lds[i_loc*72 + cq];
        uint4 b2 = *(const uint4*)&lds[i_loc*72 + cq + 8];
        u16* o = dp + (size_t)((b*M_ + m)*N_ + i0 + i_loc) * D_ + cbase + cq;
        *(uint4*)o = a;
        *(uint4*)(o + 8) = b2;
    }
}

// ============================================================
// K0v (optional, only if ws is big enough): vt fp32 -> f16, same layout.
// ============================================================
__global__ __launch_bounds__(256) void k0_vconv(const float* __restrict__ vt,
                                                u16* __restrict__ vB){
    size_t idx = ((size_t)blockIdx.x * 256 + threadIdx.x) * 8;
    const size_t total = (size_t)B_ * DV_ * N_;
    if (idx < total){
        float4 f0 = *(const float4*)(vt + idx);
        float4 f1 = *(const float4*)(vt + idx + 4);
        uint4 o;
        o.x = pk16(f0.x, f0.y);
        o.y = pk16(f0.z, f0.w);
        o.z = pk16(f1.x, f1.y);
        o.w = pk16(f1.z, f1.w);
        *(uint4*)(vB + idx) = o;
    }
}

// ============================================================
// K2: logits[b*2+m] = (sum_c weight[m,c] * barSum[b,c]) / N
// ============================================================
__global__ void k2_logits(const float* __restrict__ wgt,
                          const float* __restrict__ bar,
                          float* __restrict__ wsLog){
    const int bm = blockIdx.x;
    const int b = bm >> 1, m = bm & 1;
    const int l = threadIdx.x; // 64
    float s = 0.f;
    #pragma unroll
    for (int k = 0; k < 8; ++k){
        const int c = l + k*64;
        s += wgt[m*DK_ + c] * bar[b*DK_ + c];
    }
    s += __shfl_xor(s, 1); s += __shfl_xor(s, 2); s += __shfl_xor(s, 4);
    s += __shfl_xor(s, 8); s += __shfl_xor(s, 16); s += __shfl_xor(s, 32);
    if (l == 0) wsLog[bm] = s * (1.f / (float)N_);
}

// ============================================================
// K3: S = q·k for both mixtures, E = exp(S/sqrt(512)) packed as f16 pair
// (m0 lo, m1 hi) into the dword that will later hold attn[b,i,j] fp32.
// Epilogue also accumulates per-row exp-sums (fp32) into wsSum via atomics
// (replaces the separate k35 rowsum pass: saves a full 134 MB E read).
// ============================================================
__global__ __launch_bounds__(256, 2) void k3_qk(const u16* __restrict__ qB,
                                                const u16* __restrict__ kB,
                                                uint32_t* __restrict__ attnE,
                                                float* __restrict__ wsSum){
    const int jt = blockIdx.x, it = blockIdx.y, b = blockIdx.z;
    const int t = threadIdx.x;
    const int w = t >> 6, l = t & 63;
    const int wi = w & 1, wj = w >> 1;
    const int l15 = l & 15, lq = l >> 4;
    __shared__ u16 lds[4 * 128 * 64];   // [tile=qk*2+m][row][c(64, swizzled granules)]

    f32x4 acc[2][4][4] = {};

    const int srow = t >> 1, shalf = t & 1;
    for (int bk = 0; bk < 4; ++bk){
        #pragma unroll
        for (int tile = 0; tile < 4; ++tile){     // 0,1 = q(m0,m1); 2,3 = k(m0,m1)
            const int qk = tile >> 1, m = tile & 1;
            const u16* sp = qk ? kB : qB;
            const int row0 = (qk ? jt : it) * 128;
            const u16* g = sp + (size_t)((b*M_ + m)*N_ + row0 + srow) * D_ + bk*64 + shalf*32;
            const uint4* gp = (const uint4*)g;
            uint4 v0 = gp[0], v1 = gp[1], v2 = gp[2], v3 = gp[3];
            u16* base = &lds[(tile*128 + srow) * 64];
            const int rs = srow & 7;
            *(uint4*)&base[((shalf*4 + 0) ^ rs) * 8] = v0;
            *(uint4*)&base[((shalf*4 + 1) ^ rs) * 8] = v1;
            *(uint4*)&base[((shalf*4 + 2) ^ rs) * 8] = v2;
            *(uint4*)&base[((shalf*4 + 3) ^ rs) * 8] = v3;
        }
        __syncthreads();
        #pragma unroll
        for (int ks = 0; ks < 2; ++ks){
            #pragma unroll
            for (int m = 0; m < 2; ++m){
                half8 a[4], bb[4];
                #pragma unroll
                for (int ti = 0; ti < 4; ++ti){
                    const int row = wi*64 + ti*16 + l15;
                    const int gr = (ks*4 + lq) ^ (row & 7);
                    a[ti] = *(const half8*)&lds[(m*128 + row)*64 + gr*8];
                }
                #pragma unroll
                for (int tj = 0; tj < 4; ++tj){
                    const int row = wj*64 + tj*16 + l15;
                    const int gr = (ks*4 + lq) ^ (row & 7);
                    bb[tj] = *(const half8*)&lds[((2 + m)*128 + row)*64 + gr*8];
                }
                #pragma unroll
                for (int ti = 0; ti < 4; ++ti)
                    #pragma unroll
                    for (int tj = 0; tj < 4; ++tj)
                        acc[m][ti][tj] = __builtin_amdgcn_mfma_f32_16x16x32_f16(
                            a[ti], bb[tj], acc[m][ti][tj], 0, 0, 0);
            }
        }
        __syncthreads();
    }

    const float INVT = 0.04419417382415922f;   // 1/sqrt(512)
    uint32_t* op = attnE + (size_t)b * N_ * N_;
    const int ibase = it*128 + wi*64;
    const int jbase = jt*128 + wj*64;
    #pragma unroll
    for (int ti = 0; ti < 4; ++ti){
        float rs[2][4] = {};   // [mixture][rr] partial row sums over this wave's j
        #pragma unroll
        for (int tj = 0; tj < 4; ++tj){
            #pragma unroll
            for (int rr = 0; rr < 4; ++rr){
                const int i = ibase + ti*16 + lq*4 + rr;   // C/D: row=(l>>4)*4+reg
                const int j = jbase + tj*16 + l15;         //      col=l&15
                const float e0 = __expf(acc[0][ti][tj][rr] * INVT);
                const float e1 = __expf(acc[1][ti][tj][rr] * INVT);
                op[(size_t)i * N_ + j] = pk16(e0, e1);
                rs[0][rr] += e0;
                rs[1][rr] += e1;
            }
        }
        #pragma unroll
        for (int m2 = 0; m2 < 2; ++m2){
            #pragma unroll
            for (int rr = 0; rr < 4; ++rr){
                float s = rs[m2][rr];
                s += __shfl_xor(s, 1); s += __shfl_xor(s, 2);
                s += __shfl_xor(s, 4); s += __shfl_xor(s, 8);
                if (l15 == 0)
                    atomicAdd(&wsSum[(size_t)(b*M_ + m2)*N_ + ibase + ti*16 + lq*4 + rr], s);
            }
        }
    }
}

// ============================================================
// K4 v3: NO LDS. 256 threads = 4 waves; wave w = dv quarter (128 dv = 8 n),
// 32 rows (2 A-frags). B-frags read directly from global vB (L2: v[b]=2MB).
// E + B double-buffered in registers, prefetched one chunk ahead.
// In-place attn overwrite guarded by one raw s_barrier/chunk: each wave's
// av(c) compute drains its E(c) loads BEFORE the barrier, so post-barrier
// stores cannot clobber pending reads; prefetches stay in flight across it.
// ============================================================
template<bool HASVB>
__global__ __launch_bounds__(256, 2) void k4_pv(const float* __restrict__ vt,
                                                const u16* __restrict__ vB,
                                                const float* __restrict__ wsLog,
                                                const float* __restrict__ wsSum,
                                                uint32_t* __restrict__ attnE,
                                                float* __restrict__ outO){
    const int tile = blockIdx.x, b = blockIdx.y;
    const int i0 = tile * 32;
    const int t = threadIdx.x, l = t & 63;
    const int dvq = t >> 6;                       // wave id = dv quarter
    const int l15 = l & 15, lq = l >> 4;

    const float lg0 = wsLog[b*2 + 0], lg1 = wsLog[b*2 + 1];
    const float pi0 = 1.f / (1.f + __expf(lg1 - lg0));
    const float pi1 = 1.f / (1.f + __expf(lg0 - lg1));

    float p0[2], p1[2];
    uint32_t* erow[2];
    #pragma unroll
    for (int rg = 0; rg < 2; ++rg){
        const int row = i0 + rg*16 + l15;
        p0[rg] = pi0 / wsSum[(size_t)(b*M_ + 0)*N_ + row];
        p1[rg] = pi1 / wsSum[(size_t)(b*M_ + 1)*N_ + row];
        erow[rg] = attnE + (size_t)(b*N_ + row) * N_;
    }

    const u16*   vb16 = vB + (size_t)(b*DV_ + dvq*128 + l15)*N_ + lq*8;
    const float* vb32 = vt + (size_t)(b*DV_ + dvq*128 + l15)*N_ + lq*8;

    f32x4 acc[2][8] = {};
    uint4 eA[2][2], eB[2][2];
    half8 bA[8], bB[8];

    auto loadE = [&](uint4 (&e)[2][2], int c){
        #pragma unroll
        for (int rg = 0; rg < 2; ++rg){
            const uint4* p = (const uint4*)(erow[rg] + c*32 + lq*8);
            e[rg][0] = p[0];
            e[rg][1] = p[1];
        }
    };
    auto loadB = [&](half8 (&bb)[8], int c){
        #pragma unroll
        for (int n = 0; n < 8; ++n){
            if (HASVB){
                bb[n] = *(const half8*)(vb16 + (size_t)n*16*N_ + c*32);
            } else {
                const float* p = vb32 + (size_t)n*16*N_ + c*32;
                float4 f0 = *(const float4*)p;
                float4 f1 = *(const float4*)(p + 4);
                uint4 u;
                u.x = pk16(f0.x, f0.y); u.y = pk16(f0.z, f0.w);
                u.z = pk16(f1.x, f1.y); u.w = pk16(f1.z, f1.w);
                union { uint4 u; half8 h; } cv; cv.u = u;
                bb[n] = cv.h;
            }
        }
    };

    loadE(eA, 0);
    loadB(bA, 0);

    auto body = [&](int c, uint4 (&ec)[2][2], uint4 (&en)[2][2],
                    half8 (&bc)[8], half8 (&bn)[8]){
        float av[2][8];
        half8 af[2];
        #pragma unroll
        for (int rg = 0; rg < 2; ++rg){
            uint4 u0 = ec[rg][0], u1 = ec[rg][1];   // vmcnt-drains E(c) here
            av[rg][0] = p0[rg]*h2f_lo(u0.x) + p1[rg]*h2f_hi(u0.x);
            av[rg][1] = p0[rg]*h2f_lo(u0.y) + p1[rg]*h2f_hi(u0.y);
            av[rg][2] = p0[rg]*h2f_lo(u0.z) + p1[rg]*h2f_hi(u0.z);
            av[rg][3] = p0[rg]*h2f_lo(u0.w) + p1[rg]*h2f_hi(u0.w);
            av[rg][4] = p0[rg]*h2f_lo(u1.x) + p1[rg]*h2f_hi(u1.x);
            av[rg][5] = p0[rg]*h2f_lo(u1.y) + p1[rg]*h2f_hi(u1.y);
            av[rg][6] = p0[rg]*h2f_lo(u1.z) + p1[rg]*h2f_hi(u1.z);
            av[rg][7] = p0[rg]*h2f_lo(u1.w) + p1[rg]*h2f_hi(u1.w);
            uint4 ua;
            ua.x = pk16(av[rg][0], av[rg][1]);
            ua.y = pk16(av[rg][2], av[rg][3]);
            ua.z = pk16(av[rg][4], av[rg][5]);
            ua.w = pk16(av[rg][6], av[rg][7]);
            union { uint4 u; half8 h; } cv; cv.u = ua;
            af[rg] = cv.h;
        }
        // all waves have consumed E(c) into registers at this point
        __builtin_amdgcn_sched_barrier(0);
        __builtin_amdgcn_s_barrier();
        __builtin_amdgcn_sched_barrier(0);
        if (dvq < 2){   // finalize attn fp32 in place (rowgroup = dvq)
            float* ap = (float*)(erow[dvq] + c*32 + lq*8);
            *(float4*)ap       = make_float4(av[dvq][0], av[dvq][1], av[dvq][2], av[dvq][3]);
            *(float4*)(ap + 4) = make_float4(av[dvq][4], av[dvq][5], av[dvq][6], av[dvq][7]);
        }
        if (c < 63){            // prefetch next chunk (stays in flight)
            loadE(en, c + 1);
            loadB(bn, c + 1);
        }
        #pragma unroll
        for (int n = 0; n < 8; ++n){
            acc[0][n] = __builtin_amdgcn_mfma_f32_16x16x32_f16(af[0], bc[n], acc[0][n], 0, 0, 0);
            acc[1][n] = __builtin_amdgcn_mfma_f32_16x16x32_f16(af[1], bc[n], acc[1][n], 0, 0, 0);
        }
    };

    for (int c = 0; c < 64; c += 2){
        body(c,     eA, eB, bA, bB);
        body(c + 1, eB, eA, bB, bA);
    }

    #pragma unroll
    for (int n = 0; n < 8; ++n){
        #pragma unroll
        for (int rg = 0; rg < 2; ++rg){
            #pragma unroll
            for (int rr = 0; rr < 4; ++rr){
                const int i  = i0 + rg*16 + lq*4 + rr;   // C/D: row=(l>>4)*4+reg
                const int dv = dvq*128 + n*16 + l15;     //      col=l&15
                outO[(size_t)(b*N_ + i)*DV_ + dv] = acc[rg][n][rr];
            }
        }
    }
}

// ============================================================
extern "C" void kernel_launch(void* const* d_in, const int* in_sizes, int n_in,
                              void* d_out, int out_size, void* d_ws, size_t ws_size,
                              hipStream_t stream){
    const float* qt  = (const float*)d_in[0];
    const float* kt  = (const float*)d_in[1];
    const float* vt  = (const float*)d_in[2];
    const float* wgt = (const float*)d_in[3];

    float* ws    = (float*)d_ws;
    float* wsLog = ws;                                   // 16 floats
    float* wsBar = (float*)((char*)d_ws + 4096);         // 4096 floats
    float* wsSum = (float*)((char*)d_ws + 65536);        // 32768 floats (128 KiB)

    u16* stage = (u16*)d_out;                            // qB at 0, kB after it
    u16* kB = stage + QB_U16;
    uint32_t* attnE = (uint32_t*)d_out + OUT_FLOATS;     // attn region doubles as E scratch
    float* outO = (float*)d_out;

    const size_t vbBytes = (size_t)B_ * DV_ * N_ * 2;
    u16* vB = (ws_size >= (size_t)1048576 + vbBytes)
                  ? (u16*)((char*)d_ws + 1048576) : (u16*)nullptr;

    hipMemsetAsync(d_ws, 0, 262144, stream);             // zero wsLog/wsBar/wsSum

    k0_transpose<<<dim3(32, 8, 16), 256, 0, stream>>>(qt, kt, stage, wsBar);
    if (vB) k0_vconv<<<dim3(4096), 256, 0, stream>>>(vt, vB);
    k2_logits<<<dim3(16), 64, 0, stream>>>(wgt, wsBar, wsLog);
    k3_qk<<<dim3(16, 16, 8), 256, 0, stream>>>(stage, kB, attnE, wsSum);
    if (vB) k4_pv<true ><<<dim3(64, 8), 256, 0, stream>>>(vt, vB, wsLog, wsSum, attnE, outO);
    else    k4_pv<false><<<dim3(64, 8), 256, 0, stream>>>(vt, vB, wsLog, wsSum, attnE, outO);
}